// Round 8
// baseline (158.694 us; speedup 1.0000x reference)
//
#include <hip/hip_runtime.h>
#include <math.h>
#include <stdint.h>

// Problem constants: B=8, N=2048, C_IN=3, D=64, K=8, LEVELS=3, H1=256, H2=128
#define BB   8
#define NN   2048
#define BN   16384   // B*N
#define KNB  8

__device__ __forceinline__ float leaky(float v){ return v > 0.f ? v : 0.2f*v; }

// RNE float->bf16 bits (finite inputs), matches __float2bfloat16 rounding
__device__ __forceinline__ ushort f2bf(float f){
    unsigned u = __float_as_uint(f);
    return (ushort)((u + 0x7FFFu + ((u >> 16) & 1u)) >> 16);
}
__device__ __forceinline__ float bf2f(ushort h){
    return __uint_as_float(((unsigned)h) << 16);
}

using bf16x8 = __attribute__((ext_vector_type(8))) short;
using f32x4  = __attribute__((ext_vector_type(4)))  float;

#define CEF(a, b) { float mn_ = fminf(a,b), mx_ = fmaxf(a,b); (a) = mn_; (b) = mx_; }

// ---------------------------------------------------------------------------
// K1: ONE dispatch round. Grid = 512 blocks x 1024 thr = exactly 2 blocks/CU
// (round-4 verbatim — best measured config). Each block:
//   prologue A: weight-transpose slice (160 elements)
//   prologue B: PQ GEMM for rows [bid*32, bid*32+32)
//   main:       KNN tile — value-only top-8 + tree + rescan + tie cleanup.
// ---------------------------------------------------------------------------
__global__ __launch_bounds__(1024, 8) void k_front(
    const float* __restrict__ x,
    const float* __restrict__ W1, const float* __restrict__ b1,
    const float* __restrict__ g1, const float* __restrict__ be1,
    const float* __restrict__ W2,
    const float* __restrict__ Wf1, const float* __restrict__ Wf2,
    float* __restrict__ P, ushort* __restrict__ Qb,
    ushort* __restrict__ Wf1T, ushort* __restrict__ Wf2T,
    int* __restrict__ idxo)
{
    __shared__ __align__(16) char smem[51584];
    int t = threadIdx.x;
    int bid = blockIdx.x;

    // ---------------- prologue A: transpose slice (global->global) --------
    if (t < 160) {
        int e = bid * 160 + t;
        if (e < 49152) {                 // Wf1T [256][192] <- Wf1 [192][256]
            int n = e / 192, k = e % 192;
            Wf1T[e] = f2bf(Wf1[k*256 + n]);
        } else {                         // Wf2T [128][256] <- Wf2 [256][128]
            int e2 = e - 49152;          // < 32768
            int n = e2 >> 8, k = e2 & 255;
            Wf2T[e2] = f2bf(Wf2[k*128 + n]);
        }
    }

    // ---------------- prologue B: PQ GEMM, 32 rows ----------------
    {
        float* F_s = (float*)smem;             // [32][66]  8448 B
        float* W_s = (float*)(smem + 8448);    // [64][132] 33792 B
        int rb = bid * 32;

        {   // feat: 16 groups of 64 lanes (lane=d), 2 rows each
            int d = t & 63, g = t >> 6;
            float w0 = W1[d], w1 = W1[64+d], w2 = W1[128+d];
            float bb = b1[d], gg = g1[d], ee = be1[d];
            #pragma unroll
            for (int i = 0; i < 2; ++i) {
                int r = g*2 + i;
                const float* xp = &x[(rb + r)*3];
                float f = xp[0]*w0 + xp[1]*w1 + xp[2]*w2 + bb;
                F_s[r*66 + d] = leaky(f*gg + ee);
            }
        }
        {   // stage W' 64 x 128 once: W'[k][c] = W2[k + 64*(c>=64)][c&63]
            #pragma unroll
            for (int it = 0; it < 2; ++it) {
                int i2 = t + it*1024;            // 0..2047 float4 slots
                int k = i2 >> 5, c4 = (i2 & 31) * 4;
                const float* src = &W2[(k + (c4 >= 64 ? 64 : 0))*64 + (c4 & 63)];
                *(float4*)&W_s[k*132 + c4] = *(const float4*)src;
            }
        }
        __syncthreads();

        int row = t >> 5, cg = t & 31;   // 32 rows x 32 col-groups of 4
        float4 acc = make_float4(0.f, 0.f, 0.f, 0.f);
        #pragma unroll 8
        for (int kk = 0; kk < 64; ++kk) {
            float a = F_s[row*66 + kk];
            float4 wv = *(const float4*)&W_s[kk*132 + cg*4];
            acc.x = fmaf(a, wv.x, acc.x);
            acc.y = fmaf(a, wv.y, acc.y);
            acc.z = fmaf(a, wv.z, acc.z);
            acc.w = fmaf(a, wv.w, acc.w);
        }

        int r = rb + row;
        if (cg < 16) {                   // cols 0..63 -> P (fp32)
            *(float4*)&P[r*64 + cg*4] = acc;
        } else {                         // cols 64..127 -> Q (bf16)
            union { ushort u[4]; uint2 v; } pk;
            pk.u[0] = f2bf(acc.x); pk.u[1] = f2bf(acc.y);
            pk.u[2] = f2bf(acc.z); pk.u[3] = f2bf(acc.w);
            *(uint2*)&Qb[r*64 + (cg - 16)*4] = pk.v;
        }
    }
    __syncthreads();   // PQ smem dead; knn reuses it

    // ---------------- KNN tile (round-1-verbatim algorithm) ----------------
    float4* sp    = (float4*)smem;                // [2048] 32 KB
    float*  mg    = (float*) (smem + 32768);      // [16][32][8] 16 KB
    float*  v8buf = (float*) (smem + 49152);      // [32]
    int*    eqbuf = (int*)   (smem + 49280);      // [32][16]
    int*    cnt   = (int*)   (smem + 51328);      // [32]
    int*    ecnt  = (int*)   (smem + 51456);      // [32]

    int b = bid >> 6;
    int qbase = (bid & 63) * 32;
    int q = t & 31, seg = t >> 5;
    int w = t >> 6, lane = t & 63;

    for (int i = t; i < NN; i += 1024) {
        float a = x[(b*NN + i)*3 + 0];
        float c = x[(b*NN + i)*3 + 1];
        float e = x[(b*NN + i)*3 + 2];
        sp[i] = make_float4(a, c, e, a*a + c*c + e*e);
    }
    __syncthreads();

    // ---- Phase A: value-only top-8 over this (q,seg)'s 64 candidates ----
    float4 qv = sp[qbase + q];
    float R[8];
    #pragma unroll
    for (int j = 0; j < 8; ++j) R[j] = 1e30f;

    int m0 = seg * 64;
    #pragma unroll 2
    for (int g = 0; g < 8; ++g) {
        float S[8];
        #pragma unroll
        for (int jj = 0; jj < 8; ++jj) {
            int m = m0 + g*8 + jj;
            float4 v = sp[m];
            float s = qv.x*v.x; s = fmaf(qv.y, v.y, s); s = fmaf(qv.z, v.z, s);
            float d2 = fmaf(-2.f, s, qv.w + v.w);
            S[jj] = fmaxf(d2, 0.f);
        }
        // Batcher odd-even mergesort, 8 elems, 19 CEs (ascending)
        CEF(S[0],S[1]); CEF(S[2],S[3]); CEF(S[4],S[5]); CEF(S[6],S[7]);
        CEF(S[0],S[2]); CEF(S[1],S[3]); CEF(S[4],S[6]); CEF(S[5],S[7]);
        CEF(S[1],S[2]); CEF(S[5],S[6]);
        CEF(S[0],S[4]); CEF(S[1],S[5]); CEF(S[2],S[6]); CEF(S[3],S[7]);
        CEF(S[2],S[4]); CEF(S[3],S[5]);
        CEF(S[1],S[2]); CEF(S[3],S[4]); CEF(S[5],S[6]);
        // keep 8 smallest of R ∪ S
        #pragma unroll
        for (int j = 0; j < 8; ++j) R[j] = fminf(R[j], S[7-j]);
        CEF(R[0],R[4]); CEF(R[1],R[5]); CEF(R[2],R[6]); CEF(R[3],R[7]);
        CEF(R[0],R[2]); CEF(R[1],R[3]); CEF(R[4],R[6]); CEF(R[5],R[7]);
        CEF(R[0],R[1]); CEF(R[2],R[3]); CEF(R[4],R[5]); CEF(R[6],R[7]);
    }

    // ---- Phase A2a: intra-wave merge (seg 2w with seg 2w+1) ----
    {
        float Rp[8];
        #pragma unroll
        for (int j = 0; j < 8; ++j) Rp[j] = __shfl_xor(R[j], 32, 64);
        float C[8];
        #pragma unroll
        for (int j = 0; j < 8; ++j) C[j] = fminf(R[j], Rp[7-j]);
        CEF(C[0],C[4]); CEF(C[1],C[5]); CEF(C[2],C[6]); CEF(C[3],C[7]);
        CEF(C[0],C[2]); CEF(C[1],C[3]); CEF(C[4],C[6]); CEF(C[5],C[7]);
        CEF(C[0],C[1]); CEF(C[2],C[3]); CEF(C[4],C[5]); CEF(C[6],C[7]);
        if (lane < 32) {
            #pragma unroll
            for (int j = 0; j < 8; ++j) mg[(w*32 + lane)*8 + j] = C[j];
        }
    }

    // ---- Phase A2b: 4-level tree 16 -> 1, value-only ----
    #pragma unroll
    for (int lvl = 0; lvl < 4; ++lvl) {
        int Pn = 8 >> lvl;          // pairs per query
        int sh = 3 - lvl;
        bool active = (t < 32*Pn);
        float C[8];
        int qq = 0, p = 0;
        __syncthreads();
        if (active) {
            qq = t >> sh; p = t & (Pn - 1);
            float A[8], Bv[8];
            #pragma unroll
            for (int j = 0; j < 8; ++j) {
                A[j]  = mg[((2*p)*32 + qq)*8 + j];
                Bv[j] = mg[((2*p + 1)*32 + qq)*8 + j];
            }
            #pragma unroll
            for (int j = 0; j < 8; ++j) C[j] = fminf(A[j], Bv[7-j]);
            CEF(C[0],C[4]); CEF(C[1],C[5]); CEF(C[2],C[6]); CEF(C[3],C[7]);
            CEF(C[0],C[2]); CEF(C[1],C[3]); CEF(C[4],C[6]); CEF(C[5],C[7]);
            CEF(C[0],C[1]); CEF(C[2],C[3]); CEF(C[4],C[5]); CEF(C[6],C[7]);
        }
        __syncthreads();
        if (active) {
            if (Pn > 1) {
                #pragma unroll
                for (int j = 0; j < 8; ++j) mg[(p*32 + qq)*8 + j] = C[j];
            } else {
                v8buf[qq] = C[7];
            }
        }
    }
    if (t >= 32 && t < 64)  cnt[t - 32] = 0;
    if (t >= 64 && t < 96)  ecnt[t - 64] = 0;
    __syncthreads();

    // ---- Phase B: broadcast-layout index recovery ----
    {
        float v8 = v8buf[q];
        int obase = (b*NN + qbase + q)*KNB;
        #pragma unroll 4
        for (int jj = 0; jj < 64; ++jj) {
            int m = m0 + jj;
            float4 v = sp[m];                       // broadcast across 32 lanes
            float s = qv.x*v.x; s = fmaf(qv.y, v.y, s); s = fmaf(qv.z, v.z, s);
            float d2 = fmaf(-2.f, s, qv.w + v.w);
            d2 = fmaxf(d2, 0.f);
            if (d2 <= v8) {
                if (d2 < v8) {
                    int slot = atomicAdd(&cnt[q], 1);    // cLT <= 7 guaranteed
                    idxo[obase + slot] = b*NN + m;
                } else {
                    int slot = atomicAdd(&ecnt[q], 1);
                    if (slot < 16) eqbuf[q*16 + slot] = m;
                }
            }
        }
    }
    __syncthreads();

    // ---- cleanup: fill remaining slots with lowest-index ties at v8 ----
    if (t < 32) {
        int qq = t;
        int cLT = cnt[qq];                 // < 8 by definition of v8
        int ne = ecnt[qq]; if (ne > 16) ne = 16;
        int need = 8 - cLT;
        int obase = (b*NN + qbase + qq)*KNB;
        for (int k = 0; k < need; ++k) {
            int best = 0x7FFFFFFF, bi = -1;
            for (int i = 0; i < ne; ++i) {
                int v = eqbuf[qq*16 + i];
                if (v < best) { best = v; bi = i; }
            }
            if (bi >= 0) {
                eqbuf[qq*16 + bi] = 0x7FFFFFFF;
                idxo[obase + cLT + k] = b*NN + best;
            }
        }
    }
}

// ---------------------------------------------------------------------------
// K2: mega-fusion, 8-WAVE blocks for full occupancy.
//   16 rows/block, 1024 blocks, 512 thr (8 waves), __launch_bounds__(512,8)
//   -> VGPR cap 64, 4 blocks/CU x 8 waves = 32 waves/CU (100% slots; was 16).
//   Phase A: 2 rows/wave (half the serial chain depth of the 4-wave version).
//   h1: wave owns 32 cols (2 n-tiles, acc 8 regs); h2: wave owns 16 cols.
// ---------------------------------------------------------------------------
__global__ __launch_bounds__(512, 8) void k_fuse(
    const float* __restrict__ x,
    const float* __restrict__ P, const ushort* __restrict__ Qb,
    const int* __restrict__ idx,
    const float* __restrict__ Ws1, const float* __restrict__ bs1,
    const float* __restrict__ Ws2, const float* __restrict__ bs2,
    const float* __restrict__ b2, const float* __restrict__ g2,
    const float* __restrict__ be2,
    const ushort* __restrict__ Wf1T, const float* __restrict__ bf1,
    const float* __restrict__ gf1, const float* __restrict__ bef1,
    const ushort* __restrict__ Wf2T, const float* __restrict__ bf2,
    const float* __restrict__ gf2, const float* __restrict__ bef2,
    const float* __restrict__ Wf3, const float* __restrict__ bf3,
    float* __restrict__ out)
{
    __shared__ __align__(16) char smem[9984];
    ushort* A_s  = (ushort*)smem;            // [16][200] bf16 (aliased w/ h1_s)
    ushort* h1_s = (ushort*)smem;            // [16][264] bf16 (8448 B)
    float*  pd   = (float*) (smem + 8448);   // [16][8][3] = 1536 B

    int t = threadIdx.x, w = t >> 6, lane = t & 63;   // w in 0..7
    int rb = blockIdx.x * 16;
    int l15 = lane & 15, kg = lane >> 4, kb = kg * 8;

    // ---- phase A: fw + gather-max -> A_s (wave w: rows w*2, w*2+1) ----
    {
        float ws1a = Ws1[lane], ws1b = Ws1[64+lane], ws1c = Ws1[128+lane];
        float bs1v = bs1[lane];
        float ws2a = Ws2[lane*3+0], ws2b = Ws2[lane*3+1], ws2c = Ws2[lane*3+2];
        float bs20 = bs2[0], bs21 = bs2[1], bs22 = bs2[2];
        float g2v = g2[lane], be2v = be2[lane], b2v = b2[lane];

        int p0 = rb + w*2;
        #pragma unroll
        for (int i = 0; i < 2; ++i) {
            int p = p0 + i;
            int nb[8];
            #pragma unroll
            for (int j = 0; j < 8; ++j) nb[j] = idx[p*KNB + j];
            float Pv = P[p*64 + lane] + b2v;
            // issue all 8 gathers before the fw dependency chain
            float qg[8];
            #pragma unroll
            for (int j = 0; j < 8; ++j) qg[j] = bf2f(Qb[nb[j]*64 + lane]);
            float x0 = x[p*3+0], x1 = x[p*3+1], x2 = x[p*3+2];
            float h = fmaxf(fmaf(x2, ws1c, fmaf(x1, ws1b, fmaf(x0, ws1a, bs1v))), 0.f);
            float s0 = h*ws2a, s1 = h*ws2b, s2 = h*ws2c;
            #pragma unroll
            for (int off = 32; off; off >>= 1) {
                s0 += __shfl_xor(s0, off, 64);
                s1 += __shfl_xor(s1, off, 64);
                s2 += __shfl_xor(s2, off, 64);
            }
            float fw0 = 1.f/(1.f + expf(-(s0 + bs20)));
            float fw1 = 1.f/(1.f + expf(-(s1 + bs21)));
            float fw2 = 1.f/(1.f + expf(-(s2 + bs22)));
            float mx = -1e30f;
            #pragma unroll
            for (int j = 0; j < 8; ++j)
                mx = fmaxf(mx, leaky((Pv + qg[j])*g2v + be2v));
            int r = w*2 + i;
            A_s[r*200 + lane]       = f2bf(mx * fw0);
            A_s[r*200 + 64 + lane]  = f2bf(mx * fw1);
            A_s[r*200 + 128 + lane] = f2bf(mx * fw2);
        }
    }
    __syncthreads();

    // ---- h1 = leaky((A @ Wf1 + bf1)*gf1 + bef1): 16 x 256, wave owns 32 cols
    f32x4 acc[2];
    #pragma unroll
    for (int n2 = 0; n2 < 2; ++n2)
        #pragma unroll
        for (int i = 0; i < 4; ++i) acc[n2][i] = 0.f;

    {
        const ushort* Bb = Wf1T + (w*32 + l15)*192 + kb;   // col = w*32+n2*16+l15
        #pragma unroll
        for (int k0 = 0; k0 < 192; k0 += 32) {
            bf16x8 a = *(const bf16x8*)&A_s[l15*200 + k0 + kb];
            #pragma unroll
            for (int n2 = 0; n2 < 2; ++n2) {
                bf16x8 b = *(const bf16x8*)&Bb[n2*(16*192) + k0];
                acc[n2] = __builtin_amdgcn_mfma_f32_16x16x32_bf16(a, b, acc[n2], 0, 0, 0);
            }
        }
    }
    __syncthreads();   // all A_s reads done; safe to overwrite with h1_s

    #pragma unroll
    for (int n2 = 0; n2 < 2; ++n2) {
        int c = w*32 + n2*16 + l15;
        float bv = bf1[c], gv = gf1[c], ev = bef1[c];
        #pragma unroll
        for (int rg = 0; rg < 4; ++rg) {
            int r = kg*4 + rg;                 // 16x16 C-layout: row=(lane>>4)*4+reg
            float v = leaky((acc[n2][rg] + bv)*gv + ev);
            h1_s[r*264 + c] = f2bf(v);
        }
    }
    __syncthreads();

    // ---- h2 = leaky((h1 @ Wf2 + bf2)*gf2 + bef2): 16 x 128, wave owns 16 cols
    f32x4 acc2;
    #pragma unroll
    for (int i = 0; i < 4; ++i) acc2[i] = 0.f;

    {
        const ushort* Bb2 = Wf2T + (w*16 + l15)*256 + kb;  // col = w*16+l15
        #pragma unroll
        for (int k0 = 0; k0 < 256; k0 += 32) {
            bf16x8 a = *(const bf16x8*)&h1_s[l15*264 + k0 + kb];
            bf16x8 b = *(const bf16x8*)&Bb2[k0];
            acc2 = __builtin_amdgcn_mfma_f32_16x16x32_bf16(a, b, acc2, 0, 0, 0);
        }
    }

    // ---- epilogue: per-row delta partials over this wave's 16 cols ----
    {
        int c = w*16 + l15;
        float bv = bf2[c], gv = gf2[c], ev = bef2[c];
        float w30 = Wf3[c*3+0], w31 = Wf3[c*3+1], w32 = Wf3[c*3+2];
        #pragma unroll
        for (int rg = 0; rg < 4; ++rg) {
            float v = leaky((acc2[rg] + bv)*gv + ev);
            float d0 = v*w30, d1 = v*w31, d2 = v*w32;
            #pragma unroll
            for (int off = 8; off; off >>= 1) {  // reduce within 16-lane col group
                d0 += __shfl_xor(d0, off, 64);
                d1 += __shfl_xor(d1, off, 64);
                d2 += __shfl_xor(d2, off, 64);
            }
            int r = kg*4 + rg;
            if (l15 < 3) {
                float dl = (l15 == 0) ? d0 : (l15 == 1 ? d1 : d2);
                pd[(r*8 + w)*3 + l15] = dl;      // pd does NOT alias h1_s
            }
        }
    }
    __syncthreads();

    if (t < 48) {
        int r = t / 3, l = t - r*3;
        float delta = bf3[l];
        #pragma unroll
        for (int ww = 0; ww < 8; ++ww) delta += pd[(r*8 + ww)*3 + l];
        out[(rb + r)*3 + l] = x[(rb + r)*3 + l] + 0.1f*delta;
    }
}

// ---------------------------------------------------------------------------
extern "C" void kernel_launch(void* const* d_in, const int* in_sizes, int n_in,
                              void* d_out, int out_size, void* d_ws, size_t ws_size,
                              hipStream_t stream)
{
    const float* x    = (const float*)d_in[0];
    const float* W1   = (const float*)d_in[1];
    const float* b1   = (const float*)d_in[2];
    const float* g1   = (const float*)d_in[3];
    const float* be1  = (const float*)d_in[4];
    const float* W2   = (const float*)d_in[5];
    const float* b2   = (const float*)d_in[6];
    const float* g2   = (const float*)d_in[7];
    const float* be2  = (const float*)d_in[8];
    const float* Ws1  = (const float*)d_in[9];
    const float* bs1  = (const float*)d_in[10];
    const float* Ws2  = (const float*)d_in[11];
    const float* bs2  = (const float*)d_in[12];
    const float* Wf1  = (const float*)d_in[13];
    const float* bf1  = (const float*)d_in[14];
    const float* gf1  = (const float*)d_in[15];
    const float* bef1 = (const float*)d_in[16];
    const float* Wf2  = (const float*)d_in[17];
    const float* bf2  = (const float*)d_in[18];
    const float* gf2  = (const float*)d_in[19];
    const float* bef2 = (const float*)d_in[20];
    const float* Wf3  = (const float*)d_in[21];
    const float* bf3  = (const float*)d_in[22];
    float* out = (float*)d_out;

    char* ws = (char*)d_ws;
    int*    idx   = (int*)   (ws + 0);             // 512 KB
    ushort* Wf1T  = (ushort*)(ws + (1u << 20));    // 96 KB
    ushort* Wf2T  = (ushort*)(ws + (1u << 20) + (512u << 10)); // 64 KB
    float*  P     = (float*) (ws + (2u  << 20));   // 4 MB   [BN][64] fp32
    ushort* Qb    = (ushort*)(ws + (6u  << 20));   // 2 MB   [BN][64] bf16

    k_front<<<512, 1024, 0, stream>>>(x, W1, b1, g1, be1, W2, Wf1, Wf2,
                                      P, Qb, Wf1T, Wf2T, idx);
    k_fuse<<<BN/16, 512, 0, stream>>>(x, P, Qb, idx, Ws1, bs1, Ws2, bs2, b2, g2, be2,
                                      Wf1T, bf1, gf1, bef1, Wf2T, bf2, gf2, bef2,
                                      Wf3, bf3, out);
}

// Round 9
// 154.688 us; speedup vs baseline: 1.0259x; 1.0259x over previous
//
#include <hip/hip_runtime.h>
#include <math.h>
#include <stdint.h>

// Problem constants: B=8, N=2048, C_IN=3, D=64, K=8, LEVELS=3, H1=256, H2=128
#define BB   8
#define NN   2048
#define BN   16384   // B*N
#define KNB  8

__device__ __forceinline__ float leaky(float v){ return v > 0.f ? v : 0.2f*v; }

// RNE float->bf16 bits (finite inputs), matches __float2bfloat16 rounding
__device__ __forceinline__ ushort f2bf(float f){
    unsigned u = __float_as_uint(f);
    return (ushort)((u + 0x7FFFu + ((u >> 16) & 1u)) >> 16);
}
__device__ __forceinline__ float bf2f(ushort h){
    return __uint_as_float(((unsigned)h) << 16);
}

using bf16x8 = __attribute__((ext_vector_type(8))) short;
using f32x4  = __attribute__((ext_vector_type(4)))  float;

#define CEF(a, b) { float mn_ = fminf(a,b), mx_ = fmaxf(a,b); (a) = mn_; (b) = mx_; }

// ---------------------------------------------------------------------------
// K1: ONE dispatch round. Grid = 512 blocks x 1024 thr = exactly 2 blocks/CU
// (round-4 verbatim — best measured config, 156.2 us total). Each block:
//   prologue A: weight-transpose slice (160 elements)
//   prologue B: PQ GEMM for rows [bid*32, bid*32+32)
//   main:       KNN tile — value-only top-8 + tree + rescan + tie cleanup.
// ---------------------------------------------------------------------------
__global__ __launch_bounds__(1024, 8) void k_front(
    const float* __restrict__ x,
    const float* __restrict__ W1, const float* __restrict__ b1,
    const float* __restrict__ g1, const float* __restrict__ be1,
    const float* __restrict__ W2,
    const float* __restrict__ Wf1, const float* __restrict__ Wf2,
    float* __restrict__ P, ushort* __restrict__ Qb,
    ushort* __restrict__ Wf1T, ushort* __restrict__ Wf2T,
    int* __restrict__ idxo)
{
    __shared__ __align__(16) char smem[51584];
    int t = threadIdx.x;
    int bid = blockIdx.x;

    // ---------------- prologue A: transpose slice (global->global) --------
    if (t < 160) {
        int e = bid * 160 + t;
        if (e < 49152) {                 // Wf1T [256][192] <- Wf1 [192][256]
            int n = e / 192, k = e % 192;
            Wf1T[e] = f2bf(Wf1[k*256 + n]);
        } else {                         // Wf2T [128][256] <- Wf2 [256][128]
            int e2 = e - 49152;          // < 32768
            int n = e2 >> 8, k = e2 & 255;
            Wf2T[e2] = f2bf(Wf2[k*128 + n]);
        }
    }

    // ---------------- prologue B: PQ GEMM, 32 rows ----------------
    {
        float* F_s = (float*)smem;             // [32][66]  8448 B
        float* W_s = (float*)(smem + 8448);    // [64][132] 33792 B
        int rb = bid * 32;

        {   // feat: 16 groups of 64 lanes (lane=d), 2 rows each
            int d = t & 63, g = t >> 6;
            float w0 = W1[d], w1 = W1[64+d], w2 = W1[128+d];
            float bb = b1[d], gg = g1[d], ee = be1[d];
            #pragma unroll
            for (int i = 0; i < 2; ++i) {
                int r = g*2 + i;
                const float* xp = &x[(rb + r)*3];
                float f = xp[0]*w0 + xp[1]*w1 + xp[2]*w2 + bb;
                F_s[r*66 + d] = leaky(f*gg + ee);
            }
        }
        {   // stage W' 64 x 128 once: W'[k][c] = W2[k + 64*(c>=64)][c&63]
            #pragma unroll
            for (int it = 0; it < 2; ++it) {
                int i2 = t + it*1024;            // 0..2047 float4 slots
                int k = i2 >> 5, c4 = (i2 & 31) * 4;
                const float* src = &W2[(k + (c4 >= 64 ? 64 : 0))*64 + (c4 & 63)];
                *(float4*)&W_s[k*132 + c4] = *(const float4*)src;
            }
        }
        __syncthreads();

        int row = t >> 5, cg = t & 31;   // 32 rows x 32 col-groups of 4
        float4 acc = make_float4(0.f, 0.f, 0.f, 0.f);
        #pragma unroll 8
        for (int kk = 0; kk < 64; ++kk) {
            float a = F_s[row*66 + kk];
            float4 wv = *(const float4*)&W_s[kk*132 + cg*4];
            acc.x = fmaf(a, wv.x, acc.x);
            acc.y = fmaf(a, wv.y, acc.y);
            acc.z = fmaf(a, wv.z, acc.z);
            acc.w = fmaf(a, wv.w, acc.w);
        }

        int r = rb + row;
        if (cg < 16) {                   // cols 0..63 -> P (fp32)
            *(float4*)&P[r*64 + cg*4] = acc;
        } else {                         // cols 64..127 -> Q (bf16)
            union { ushort u[4]; uint2 v; } pk;
            pk.u[0] = f2bf(acc.x); pk.u[1] = f2bf(acc.y);
            pk.u[2] = f2bf(acc.z); pk.u[3] = f2bf(acc.w);
            *(uint2*)&Qb[r*64 + (cg - 16)*4] = pk.v;
        }
    }
    __syncthreads();   // PQ smem dead; knn reuses it

    // ---------------- KNN tile (round-1-verbatim algorithm) ----------------
    float4* sp    = (float4*)smem;                // [2048] 32 KB
    float*  mg    = (float*) (smem + 32768);      // [16][32][8] 16 KB
    float*  v8buf = (float*) (smem + 49152);      // [32]
    int*    eqbuf = (int*)   (smem + 49280);      // [32][16]
    int*    cnt   = (int*)   (smem + 51328);      // [32]
    int*    ecnt  = (int*)   (smem + 51456);      // [32]

    int b = bid >> 6;
    int qbase = (bid & 63) * 32;
    int q = t & 31, seg = t >> 5;
    int w = t >> 6, lane = t & 63;

    for (int i = t; i < NN; i += 1024) {
        float a = x[(b*NN + i)*3 + 0];
        float c = x[(b*NN + i)*3 + 1];
        float e = x[(b*NN + i)*3 + 2];
        sp[i] = make_float4(a, c, e, a*a + c*c + e*e);
    }
    __syncthreads();

    // ---- Phase A: value-only top-8 over this (q,seg)'s 64 candidates ----
    float4 qv = sp[qbase + q];
    float R[8];
    #pragma unroll
    for (int j = 0; j < 8; ++j) R[j] = 1e30f;

    int m0 = seg * 64;
    #pragma unroll 2
    for (int g = 0; g < 8; ++g) {
        float S[8];
        #pragma unroll
        for (int jj = 0; jj < 8; ++jj) {
            int m = m0 + g*8 + jj;
            float4 v = sp[m];
            float s = qv.x*v.x; s = fmaf(qv.y, v.y, s); s = fmaf(qv.z, v.z, s);
            float d2 = fmaf(-2.f, s, qv.w + v.w);
            S[jj] = fmaxf(d2, 0.f);
        }
        // Batcher odd-even mergesort, 8 elems, 19 CEs (ascending)
        CEF(S[0],S[1]); CEF(S[2],S[3]); CEF(S[4],S[5]); CEF(S[6],S[7]);
        CEF(S[0],S[2]); CEF(S[1],S[3]); CEF(S[4],S[6]); CEF(S[5],S[7]);
        CEF(S[1],S[2]); CEF(S[5],S[6]);
        CEF(S[0],S[4]); CEF(S[1],S[5]); CEF(S[2],S[6]); CEF(S[3],S[7]);
        CEF(S[2],S[4]); CEF(S[3],S[5]);
        CEF(S[1],S[2]); CEF(S[3],S[4]); CEF(S[5],S[6]);
        // keep 8 smallest of R ∪ S
        #pragma unroll
        for (int j = 0; j < 8; ++j) R[j] = fminf(R[j], S[7-j]);
        CEF(R[0],R[4]); CEF(R[1],R[5]); CEF(R[2],R[6]); CEF(R[3],R[7]);
        CEF(R[0],R[2]); CEF(R[1],R[3]); CEF(R[4],R[6]); CEF(R[5],R[7]);
        CEF(R[0],R[1]); CEF(R[2],R[3]); CEF(R[4],R[5]); CEF(R[6],R[7]);
    }

    // ---- Phase A2a: intra-wave merge (seg 2w with seg 2w+1) ----
    {
        float Rp[8];
        #pragma unroll
        for (int j = 0; j < 8; ++j) Rp[j] = __shfl_xor(R[j], 32, 64);
        float C[8];
        #pragma unroll
        for (int j = 0; j < 8; ++j) C[j] = fminf(R[j], Rp[7-j]);
        CEF(C[0],C[4]); CEF(C[1],C[5]); CEF(C[2],C[6]); CEF(C[3],C[7]);
        CEF(C[0],C[2]); CEF(C[1],C[3]); CEF(C[4],C[6]); CEF(C[5],C[7]);
        CEF(C[0],C[1]); CEF(C[2],C[3]); CEF(C[4],C[5]); CEF(C[6],C[7]);
        if (lane < 32) {
            #pragma unroll
            for (int j = 0; j < 8; ++j) mg[(w*32 + lane)*8 + j] = C[j];
        }
    }

    // ---- Phase A2b: 4-level tree 16 -> 1, value-only ----
    #pragma unroll
    for (int lvl = 0; lvl < 4; ++lvl) {
        int Pn = 8 >> lvl;          // pairs per query
        int sh = 3 - lvl;
        bool active = (t < 32*Pn);
        float C[8];
        int qq = 0, p = 0;
        __syncthreads();
        if (active) {
            qq = t >> sh; p = t & (Pn - 1);
            float A[8], Bv[8];
            #pragma unroll
            for (int j = 0; j < 8; ++j) {
                A[j]  = mg[((2*p)*32 + qq)*8 + j];
                Bv[j] = mg[((2*p + 1)*32 + qq)*8 + j];
            }
            #pragma unroll
            for (int j = 0; j < 8; ++j) C[j] = fminf(A[j], Bv[7-j]);
            CEF(C[0],C[4]); CEF(C[1],C[5]); CEF(C[2],C[6]); CEF(C[3],C[7]);
            CEF(C[0],C[2]); CEF(C[1],C[3]); CEF(C[4],C[6]); CEF(C[5],C[7]);
            CEF(C[0],C[1]); CEF(C[2],C[3]); CEF(C[4],C[5]); CEF(C[6],C[7]);
        }
        __syncthreads();
        if (active) {
            if (Pn > 1) {
                #pragma unroll
                for (int j = 0; j < 8; ++j) mg[(p*32 + qq)*8 + j] = C[j];
            } else {
                v8buf[qq] = C[7];
            }
        }
    }
    if (t >= 32 && t < 64)  cnt[t - 32] = 0;
    if (t >= 64 && t < 96)  ecnt[t - 64] = 0;
    __syncthreads();

    // ---- Phase B: broadcast-layout index recovery ----
    {
        float v8 = v8buf[q];
        int obase = (b*NN + qbase + q)*KNB;
        #pragma unroll 4
        for (int jj = 0; jj < 64; ++jj) {
            int m = m0 + jj;
            float4 v = sp[m];                       // broadcast across 32 lanes
            float s = qv.x*v.x; s = fmaf(qv.y, v.y, s); s = fmaf(qv.z, v.z, s);
            float d2 = fmaf(-2.f, s, qv.w + v.w);
            d2 = fmaxf(d2, 0.f);
            if (d2 <= v8) {
                if (d2 < v8) {
                    int slot = atomicAdd(&cnt[q], 1);    // cLT <= 7 guaranteed
                    idxo[obase + slot] = b*NN + m;
                } else {
                    int slot = atomicAdd(&ecnt[q], 1);
                    if (slot < 16) eqbuf[q*16 + slot] = m;
                }
            }
        }
    }
    __syncthreads();

    // ---- cleanup: fill remaining slots with lowest-index ties at v8 ----
    if (t < 32) {
        int qq = t;
        int cLT = cnt[qq];                 // < 8 by definition of v8
        int ne = ecnt[qq]; if (ne > 16) ne = 16;
        int need = 8 - cLT;
        int obase = (b*NN + qbase + qq)*KNB;
        for (int k = 0; k < need; ++k) {
            int best = 0x7FFFFFFF, bi = -1;
            for (int i = 0; i < ne; ++i) {
                int v = eqbuf[qq*16 + i];
                if (v < best) { best = v; bi = i; }
            }
            if (bi >= 0) {
                eqbuf[qq*16 + bi] = 0x7FFFFFFF;
                idxo[obase + cLT + k] = b*NN + best;
            }
        }
    }
}

// ---------------------------------------------------------------------------
// K2: mega-fusion (round-4 verbatim — best measured config).
//   16 rows/block, 1024 blocks, 256 thr (4 waves); mfma_f32_16x16x32_bf16;
//   B fragments read directly from L2-resident Wf1T/Wf2T.
// ---------------------------------------------------------------------------
__global__ __launch_bounds__(256, 4) void k_fuse(
    const float* __restrict__ x,
    const float* __restrict__ P, const ushort* __restrict__ Qb,
    const int* __restrict__ idx,
    const float* __restrict__ Ws1, const float* __restrict__ bs1,
    const float* __restrict__ Ws2, const float* __restrict__ bs2,
    const float* __restrict__ b2, const float* __restrict__ g2,
    const float* __restrict__ be2,
    const ushort* __restrict__ Wf1T, const float* __restrict__ bf1,
    const float* __restrict__ gf1, const float* __restrict__ bef1,
    const ushort* __restrict__ Wf2T, const float* __restrict__ bf2,
    const float* __restrict__ gf2, const float* __restrict__ bef2,
    const float* __restrict__ Wf3, const float* __restrict__ bf3,
    float* __restrict__ out)
{
    __shared__ __align__(16) char smem[9216];
    ushort* A_s  = (ushort*)smem;            // [16][200] bf16 (aliased w/ h1_s)
    ushort* h1_s = (ushort*)smem;            // [16][264] bf16
    float*  pd   = (float*) (smem + 8448);   // [16][4][3]

    int t = threadIdx.x, w = t >> 6, lane = t & 63;
    int rb = blockIdx.x * 16;
    int l15 = lane & 15, kg = lane >> 4, kb = kg * 8;

    // ---- phase A: fw + gather-max -> A_s (wave w: rows w*4..w*4+3) ----
    {
        float ws1a = Ws1[lane], ws1b = Ws1[64+lane], ws1c = Ws1[128+lane];
        float bs1v = bs1[lane];
        float ws2a = Ws2[lane*3+0], ws2b = Ws2[lane*3+1], ws2c = Ws2[lane*3+2];
        float bs20 = bs2[0], bs21 = bs2[1], bs22 = bs2[2];
        float g2v = g2[lane], be2v = be2[lane], b2v = b2[lane];

        int p0 = rb + w*4;
        float Pv[4]; int nb[4][8];
        #pragma unroll
        for (int i = 0; i < 4; ++i) {
            Pv[i] = P[(p0 + i)*64 + lane] + b2v;
            #pragma unroll
            for (int j = 0; j < 8; ++j) nb[i][j] = idx[(p0 + i)*8 + j];
        }
        #pragma unroll
        for (int i = 0; i < 4; ++i) {
            int p = p0 + i;
            // issue all 8 gathers up front — latency hides under fw chain
            float qg[8];
            #pragma unroll
            for (int j = 0; j < 8; ++j) qg[j] = bf2f(Qb[nb[i][j]*64 + lane]);
            float x0 = x[p*3+0], x1 = x[p*3+1], x2 = x[p*3+2];
            float h = fmaxf(fmaf(x2, ws1c, fmaf(x1, ws1b, fmaf(x0, ws1a, bs1v))), 0.f);
            float s0 = h*ws2a, s1 = h*ws2b, s2 = h*ws2c;
            #pragma unroll
            for (int off = 32; off; off >>= 1) {
                s0 += __shfl_xor(s0, off, 64);
                s1 += __shfl_xor(s1, off, 64);
                s2 += __shfl_xor(s2, off, 64);
            }
            float fw0 = 1.f/(1.f + expf(-(s0 + bs20)));
            float fw1 = 1.f/(1.f + expf(-(s1 + bs21)));
            float fw2 = 1.f/(1.f + expf(-(s2 + bs22)));
            float mx = -1e30f;
            #pragma unroll
            for (int j = 0; j < 8; ++j)
                mx = fmaxf(mx, leaky((Pv[i] + qg[j])*g2v + be2v));
            int r = w*4 + i;
            A_s[r*200 + lane]       = f2bf(mx * fw0);
            A_s[r*200 + 64 + lane]  = f2bf(mx * fw1);
            A_s[r*200 + 128 + lane] = f2bf(mx * fw2);
        }
    }
    __syncthreads();

    // ---- h1 = leaky((A @ Wf1 + bf1)*gf1 + bef1): 16 x 256, wave owns 64 cols
    f32x4 acc[4];
    #pragma unroll
    for (int n2 = 0; n2 < 4; ++n2)
        #pragma unroll
        for (int i = 0; i < 4; ++i) acc[n2][i] = 0.f;

    {
        const ushort* Bb = Wf1T + (w*64 + l15)*192 + kb;   // col = w*64+n2*16+l15
        #pragma unroll
        for (int k0 = 0; k0 < 192; k0 += 32) {
            bf16x8 a = *(const bf16x8*)&A_s[l15*200 + k0 + kb];
            #pragma unroll
            for (int n2 = 0; n2 < 4; ++n2) {
                bf16x8 b = *(const bf16x8*)&Bb[n2*(16*192) + k0];
                acc[n2] = __builtin_amdgcn_mfma_f32_16x16x32_bf16(a, b, acc[n2], 0, 0, 0);
            }
        }
    }
    __syncthreads();   // all A_s reads done; safe to overwrite with h1_s

    #pragma unroll
    for (int n2 = 0; n2 < 4; ++n2) {
        int c = w*64 + n2*16 + l15;
        float bv = bf1[c], gv = gf1[c], ev = bef1[c];
        #pragma unroll
        for (int rg = 0; rg < 4; ++rg) {
            int r = kg*4 + rg;                 // 16x16 C-layout: row=(lane>>4)*4+reg
            float v = leaky((acc[n2][rg] + bv)*gv + ev);
            h1_s[r*264 + c] = f2bf(v);
        }
    }
    __syncthreads();

    // ---- h2 = leaky((h1 @ Wf2 + bf2)*gf2 + bef2): 16 x 128, wave owns 32 cols
    f32x4 acc2[2];
    #pragma unroll
    for (int n2 = 0; n2 < 2; ++n2)
        #pragma unroll
        for (int i = 0; i < 4; ++i) acc2[n2][i] = 0.f;

    {
        const ushort* Bb2 = Wf2T + (w*32 + l15)*256 + kb;  // col = w*32+n2*16+l15
        #pragma unroll
        for (int k0 = 0; k0 < 256; k0 += 32) {
            bf16x8 a = *(const bf16x8*)&h1_s[l15*264 + k0 + kb];
            #pragma unroll
            for (int n2 = 0; n2 < 2; ++n2) {
                bf16x8 b = *(const bf16x8*)&Bb2[n2*(16*256) + k0];
                acc2[n2] = __builtin_amdgcn_mfma_f32_16x16x32_bf16(a, b, acc2[n2], 0, 0, 0);
            }
        }
    }

    // ---- epilogue: per-row delta partials over this wave's 32 cols ----
    {
        float bv[2], gv[2], ev[2], w3[2][3];
        #pragma unroll
        for (int n2 = 0; n2 < 2; ++n2) {
            int c = w*32 + n2*16 + l15;
            bv[n2] = bf2[c]; gv[n2] = gf2[c]; ev[n2] = bef2[c];
            #pragma unroll
            for (int l = 0; l < 3; ++l) w3[n2][l] = Wf3[c*3 + l];
        }
        #pragma unroll
        for (int rg = 0; rg < 4; ++rg) {
            float d0 = 0.f, d1 = 0.f, d2 = 0.f;
            #pragma unroll
            for (int n2 = 0; n2 < 2; ++n2) {
                float v = leaky((acc2[n2][rg] + bv[n2])*gv[n2] + ev[n2]);
                d0 = fmaf(v, w3[n2][0], d0);
                d1 = fmaf(v, w3[n2][1], d1);
                d2 = fmaf(v, w3[n2][2], d2);
            }
            #pragma unroll
            for (int off = 8; off; off >>= 1) {  // reduce across the 16-lane col group
                d0 += __shfl_xor(d0, off, 64);
                d1 += __shfl_xor(d1, off, 64);
                d2 += __shfl_xor(d2, off, 64);
            }
            int r = kg*4 + rg;
            if (l15 < 3) {
                float dl = (l15 == 0) ? d0 : (l15 == 1 ? d1 : d2);
                pd[(r*4 + w)*3 + l15] = dl;
            }
        }
    }
    __syncthreads();

    if (t < 48) {
        int r = t / 3, l = t - r*3;
        float delta = pd[(r*4 + 0)*3 + l] + pd[(r*4 + 1)*3 + l]
                    + pd[(r*4 + 2)*3 + l] + pd[(r*4 + 3)*3 + l] + bf3[l];
        out[(rb + r)*3 + l] = x[(rb + r)*3 + l] + 0.1f*delta;
    }
}

// ---------------------------------------------------------------------------
extern "C" void kernel_launch(void* const* d_in, const int* in_sizes, int n_in,
                              void* d_out, int out_size, void* d_ws, size_t ws_size,
                              hipStream_t stream)
{
    const float* x    = (const float*)d_in[0];
    const float* W1   = (const float*)d_in[1];
    const float* b1   = (const float*)d_in[2];
    const float* g1   = (const float*)d_in[3];
    const float* be1  = (const float*)d_in[4];
    const float* W2   = (const float*)d_in[5];
    const float* b2   = (const float*)d_in[6];
    const float* g2   = (const float*)d_in[7];
    const float* be2  = (const float*)d_in[8];
    const float* Ws1  = (const float*)d_in[9];
    const float* bs1  = (const float*)d_in[10];
    const float* Ws2  = (const float*)d_in[11];
    const float* bs2  = (const float*)d_in[12];
    const float* Wf1  = (const float*)d_in[13];
    const float* bf1  = (const float*)d_in[14];
    const float* gf1  = (const float*)d_in[15];
    const float* bef1 = (const float*)d_in[16];
    const float* Wf2  = (const float*)d_in[17];
    const float* bf2  = (const float*)d_in[18];
    const float* gf2  = (const float*)d_in[19];
    const float* bef2 = (const float*)d_in[20];
    const float* Wf3  = (const float*)d_in[21];
    const float* bf3  = (const float*)d_in[22];
    float* out = (float*)d_out;

    char* ws = (char*)d_ws;
    int*    idx   = (int*)   (ws + 0);             // 512 KB
    ushort* Wf1T  = (ushort*)(ws + (1u << 20));    // 96 KB
    ushort* Wf2T  = (ushort*)(ws + (1u << 20) + (512u << 10)); // 64 KB
    float*  P     = (float*) (ws + (2u  << 20));   // 4 MB   [BN][64] fp32
    ushort* Qb    = (ushort*)(ws + (6u  << 20));   // 2 MB   [BN][64] bf16

    // ONE full dispatch round: 512 blocks (2/CU on 256 CUs), PQ+transpose
    // folded into every block as a prologue.
    k_front<<<512, 1024, 0, stream>>>(x, W1, b1, g1, be1, W2, Wf1, Wf2,
                                      P, Qb, Wf1T, Wf2T, idx);
    k_fuse<<<BN/16, 256, 0, stream>>>(x, P, Qb, idx, Ws1, bs1, Ws2, bs2, b2, g2, be2,
                                      Wf1T, bf1, gf1, bef1, Wf2T, bf2, gf2, bef2,
                                      Wf3, bf3, out);
}